// Round 3
// baseline (2779.621 us; speedup 1.0000x reference)
//
#include <hip/hip_runtime.h>

// Decoder LSTM: B=32, T=511 steps, H=1024, 4H=4096, V=32000
// out = res[32][511][1024] ++ hT[32][1024] ++ cT[32][1024]  (fp32)

typedef __bf16 bf16;
typedef __bf16 bf16x4 __attribute__((ext_vector_type(4)));
typedef __bf16 bf16x8 __attribute__((ext_vector_type(8)));
typedef float f32x4 __attribute__((ext_vector_type(4)));
typedef float f32x16 __attribute__((ext_vector_type(16)));
typedef unsigned int u32x2 __attribute__((ext_vector_type(2)));
typedef unsigned int u32x4 __attribute__((ext_vector_type(4)));

#define M_TOT 16352        // 511*32 rows of x_proj
#define RES_STRIDE 523264  // 511*1024
#define HT_OFF 16744448    // 32*511*1024
#define CT_OFF 16777216    // HT_OFF + 32768

// Coherent (cross-XCD) ops: sc0 sc1 bypass the per-XCD L2, hit L3.
// saddr-form load: uniform SGPR base + per-lane 32-bit voffset.
// NOTE: inline-asm "v" operands must be ext_vector_type, not HIP's uint4 struct
// (clang: "Don't know how to handle indirect register inputs").
__device__ __forceinline__ u32x4 load_cg_sv(unsigned voff, const void* sbase) {
    u32x4 r;
    asm volatile("global_load_dwordx4 %0, %1, %2 sc0 sc1"
                 : "=v"(r) : "v"(voff), "s"(sbase));
    return r;
}
__device__ __forceinline__ void store_coherent16(void* p, u32x4 v) {
    asm volatile("global_store_dwordx4 %0, %1, off sc0 sc1" :: "v"(p), "v"(v) : "memory");
}
__device__ __forceinline__ void wait_vm0() {
    asm volatile("s_waitcnt vmcnt(0)" ::: "memory");
}
__device__ __forceinline__ unsigned pack2bf(float a, float b) {
    unsigned ua = (unsigned)__builtin_bit_cast(unsigned short, (bf16)a);
    unsigned ub = (unsigned)__builtin_bit_cast(unsigned short, (bf16)b);
    return ua | (ub << 16);
}
// fast activations: v_exp_f32 + v_rcp_f32 (on the 511-step serial chain)
__device__ __forceinline__ float fsig(float x) {
    return __builtin_amdgcn_rcpf(1.f + __expf(-x));
}
__device__ __forceinline__ float ftanh(float x) {
    float e = __expf(2.f * x);
    return 1.f - 2.f * __builtin_amdgcn_rcpf(e + 1.f);
}

// ---------- fp32 -> bf16 conversion ----------
__global__ void cvt_kernel(const float* __restrict__ src, bf16* __restrict__ dst, int n4) {
    int i = blockIdx.x * blockDim.x + threadIdx.x;
    if (i < n4) {
        float4 v = ((const float4*)src)[i];
        bf16x4 o;
        o[0] = (bf16)v.x; o[1] = (bf16)v.y; o[2] = (bf16)v.z; o[3] = (bf16)v.w;
        ((bf16x4*)dst)[i] = o;
    }
}

// ---------- init h0 as tagged 16B units: unit n = blk*128 + b*4 + (ec>>2) ----------
// unit = { pack(h0,h1), pack(h2,h3), tag, tag }, tag for initial state = 0
__global__ void init_state(const float* __restrict__ h0, u32x4* __restrict__ hxA) {
    int n = blockIdx.x * blockDim.x + threadIdx.x;
    if (n < 8192) {
        int blk = n >> 7, b = (n >> 2) & 31, e4 = n & 3;
        const float* src = h0 + b * 1024 + blk * 16 + e4 * 4;
        u32x4 v;
        v.x = pack2bf(src[0], src[1]);
        v.y = pack2bf(src[2], src[3]);
        v.z = 0u; v.w = 0u;
        hxA[n] = v;
    }
}

// ---------- x_proj GEMM -> P'' block-major: P[(t*64+blk)*2048 + gate*512 + b*16 + c] ----------
__global__ __launch_bounds__(256) void gemm_xproj(
    const int* __restrict__ tgt, const bf16* __restrict__ emb,
    const bf16* __restrict__ wih, const float* __restrict__ bih,
    const float* __restrict__ bhh, bf16* __restrict__ P)
{
    __shared__ bf16 As[128 * 72];
    __shared__ bf16 Bs[128 * 72];
    __shared__ int tok[128];

    const int tid  = threadIdx.x;
    const int lane = tid & 63;
    const int wave = tid >> 6;
    const int wm = wave & 1, wn = wave >> 1;
    const int tileM = blockIdx.y * 128;
    const int tileN = blockIdx.x * 128;

    if (tid < 128) {
        int m = tileM + tid;
        int token = 0;
        if (m < M_TOT) {
            int t = m >> 5, b = m & 31;
            token = tgt[b * 512 + t];
            if ((unsigned)token >= 32000u) token = 0;
        }
        tok[tid] = token;
    }
    __syncthreads();

    f32x4 acc[4][4] = {};

    for (int k0 = 0; k0 < 1024; k0 += 64) {
        #pragma unroll
        for (int i = 0; i < 4; ++i) {
            int chunk = i * 256 + tid;
            int row = chunk >> 3;
            int kc  = (chunk & 7) * 8;
            const bf16* srcA = emb + (long)tok[row] * 1024 + k0 + kc;
            *(uint4*)&As[row * 72 + kc] = *(const uint4*)srcA;
            const bf16* srcB = wih + (long)(tileN + row) * 1024 + k0 + kc;
            *(uint4*)&Bs[row * 72 + kc] = *(const uint4*)srcB;
        }
        __syncthreads();
        #pragma unroll
        for (int kk = 0; kk < 64; kk += 32) {
            bf16x8 a[4], b[4];
            #pragma unroll
            for (int f = 0; f < 4; ++f) {
                a[f] = *(const bf16x8*)&As[(wm * 64 + f * 16 + (lane & 15)) * 72 + kk + (lane >> 4) * 8];
                b[f] = *(const bf16x8*)&Bs[(wn * 64 + f * 16 + (lane & 15)) * 72 + kk + (lane >> 4) * 8];
            }
            #pragma unroll
            for (int mf = 0; mf < 4; ++mf)
                #pragma unroll
                for (int nf = 0; nf < 4; ++nf)
                    acc[mf][nf] = __builtin_amdgcn_mfma_f32_16x16x32_bf16(a[mf], b[nf], acc[mf][nf], 0, 0, 0);
        }
        __syncthreads();
    }

    float bias[4];
    #pragma unroll
    for (int nf = 0; nf < 4; ++nf) {
        int j = tileN + wn * 64 + nf * 16 + (lane & 15);
        bias[nf] = bih[j] + bhh[j];
    }
    #pragma unroll
    for (int mf = 0; mf < 4; ++mf) {
        int mBase = tileM + wm * 64 + mf * 16 + ((lane >> 4) * 4);
        #pragma unroll
        for (int r = 0; r < 4; ++r) {
            int m = mBase + r;
            if (m < M_TOT) {
                int t = m >> 5, bb = m & 31;
                #pragma unroll
                for (int nf = 0; nf < 4; ++nf) {
                    int j = tileN + wn * 64 + nf * 16 + (lane & 15);
                    int gate = j >> 10, jc = j & 1023;
                    int pblk = jc >> 4, pc = jc & 15;
                    P[((long)(t * 64 + pblk)) * 2048 + gate * 512 + bb * 16 + pc]
                        = (bf16)(acc[mf][nf][r] + bias[nf]);
                }
            }
        }
    }
}

// ---------- persistent LSTM: 64 blocks x 512 thr, Lamport-tagged h exchange ----------
// Exchange unit (16B, one-lane dwordx4 store => tear-free): {h0|h1, h2|h3, tag, tag}.
// Consumer at step t reads buf[t&1] expecting tag==t; producer at step t writes
// buf[(t+1)&1] with tag t+1. Safety: no block can store tag t+2 (overwriting the
// buffer a spinner at step t reads) until every block has stored tag t+1, which
// requires every block to have passed spin(t) => max drift 1 step, ping-pong safe.
__global__ __launch_bounds__(512, 1) void lstm_persist(
    const bf16* __restrict__ P, const bf16* __restrict__ whh,
    const float* __restrict__ c0, float* __restrict__ out,
    u32x4* __restrict__ hxA, u32x4* __restrict__ hxB)
{
    __shared__ bf16  hs[32 * 1024];          // h staged, XOR-swizzled (64 KB)
    __shared__ float gs[4 * 64 * 33];        // K-split partials [ks][o][b] (33.8 KB)
    __shared__ bf16  ps[2][2048];            // P'' block, double-buffered (8 KB)

    const int tid  = threadIdx.x;
    const int lane = tid & 63;
    const int wave = tid >> 6;               // 0..7
    const int blk  = blockIdx.x;

    const int tp    = wave & 1;              // col-tile: gates {0,1} or {2,3}
    const int ks    = wave >> 1;             // K quarter 0..3
    const int cc    = lane & 31;
    const int khalf = lane >> 5;
    const int o     = tp * 32 + cc;

    // ---- preload this lane's W_hh B-fragments (16 x bf16x8 = 64 VGPRs) ----
    bf16x8 wreg[16];
    {
        const int gate = tp * 2 + (cc >> 4);
        const int wRow = gate * 1024 + blk * 16 + (cc & 15);
        const bf16* wbase = whh + (long)wRow * 1024 + ks * 256 + khalf * 8;
        #pragma unroll
        for (int i = 0; i < 16; ++i) wreg[i] = *(const bf16x8*)(wbase + i * 16);
    }

    // ---- per-thread epilogue element: (eb, ec) ----
    const int eb = tid >> 4;                 // batch row 0..31
    const int ec = tid & 15;
    const int hcol = blk * 16 + ec;
    float cReg = c0[eb * 1024 + hcol];

    const int m = lane & 31;                 // A-frag row (batch)

    // ---- consumer staging constants (unit n = j*512+tid, all tid-static) ----
    const unsigned voff = (unsigned)(tid << 4);          // byte off within 8KB stripe
    const int srow = (tid >> 2) & 31;                    // the one h-row this thread stages
    const int chb  = ((tid >> 7) << 1) | ((tid & 3) >> 1);
    const int s7   = srow & 7;
    char* hsb = (char*)hs + srow * 2048 + (tid & 1) * 8;

    // ---- prologue prefetch for t=0 ----
    uint2 pv = *(const uint2*)((const char*)P + ((long)blk) * 4096 + tid * 8);
    u32x4 u[16];
    #pragma unroll
    for (int j = 0; j < 16; ++j)
        u[j] = load_cg_sv(voff, (const char*)hxA + j * 8192);

    for (int t = 0; t < 511; ++t) {
        const char* hb = (const char*)((t & 1) ? hxB : hxA);
        const unsigned exptag = (unsigned)t;

        // ---- spin: loads already in flight; poll tags, reissue until fresh ----
        for (;;) {
            wait_vm0();
            __builtin_amdgcn_sched_barrier(0);   // rule #18: pin check after waitcnt
            unsigned bad = 0;
            #pragma unroll
            for (int j = 0; j < 16; ++j) bad |= (u[j].z ^ exptag);
            if (bad == 0) break;
            #pragma unroll
            for (int j = 0; j < 16; ++j)
                u[j] = load_cg_sv(voff, hb + j * 8192);
        }

        // ---- stage h (pre-packed pairs) + P'' -> LDS ----
        #pragma unroll
        for (int j = 0; j < 16; ++j)
            *(uint2*)(hsb + (((j * 8 + chb) ^ s7) << 4)) = make_uint2(u[j].x, u[j].y);
        *(uint2*)&ps[t & 1][tid * 4] = pv;
        __syncthreads();

        // ---- K-loop: 16 x mfma_32x32x16, A from LDS, B from regs ----
        f32x16 acc = {};
        #pragma unroll
        for (int i = 0; i < 16; ++i) {
            int ch = ks * 32 + i * 2 + khalf;
            bf16x8 a = *(const bf16x8*)&hs[m * 1024 + ((ch ^ (m & 7)) << 3)];
            acc = __builtin_amdgcn_mfma_f32_32x32x16_bf16(a, wreg[i], acc, 0, 0, 0);
        }

        // ---- write partials to exchange ----
        #pragma unroll
        for (int r = 0; r < 16; ++r) {
            int b = (r & 3) + 8 * (r >> 2) + 4 * khalf;   // C/D row
            gs[(ks * 64 + o) * 33 + b] = acc[r];
        }
        __syncthreads();

        // ---- epilogue: one (eb, hcol) element per thread ----
        float g4[4];
        #pragma unroll
        for (int g = 0; g < 4; ++g) {
            int oo = (g >> 1) * 32 + (g & 1) * 16 + ec;
            float s = gs[(0 * 64 + oo) * 33 + eb] + gs[(1 * 64 + oo) * 33 + eb]
                    + gs[(2 * 64 + oo) * 33 + eb] + gs[(3 * 64 + oo) * 33 + eb];
            g4[g] = s + (float)ps[t & 1][g * 512 + eb * 16 + ec];
        }
        float ig = fsig(g4[0]);
        float fg = fsig(g4[1]);
        float gg = ftanh(g4[2]);
        float og = fsig(g4[3]);
        cReg = fg * cReg + ig * gg;
        float hnew = og * ftanh(cReg);

        if (t < 510) {
            // ---- publish h for step t+1: quad-pack via DPP, one 16B store per 4 lanes ----
            unsigned w = (unsigned)__builtin_bit_cast(unsigned short, (bf16)hnew);
            unsigned p1  = (unsigned)__builtin_amdgcn_mov_dpp((int)w,   0xB1, 0xF, 0xF, true); // xor1
            unsigned w01 = (tid & 1) ? (p1 | (w << 16)) : (w | (p1 << 16));
            unsigned w23 = (unsigned)__builtin_amdgcn_mov_dpp((int)w01, 0x4E, 0xF, 0xF, true); // xor2
            char* hob = (char*)((t & 1) ? hxA : hxB);
            if ((tid & 3) == 0) {
                u32x4 st;
                st.x = w01; st.y = w23; st.z = (unsigned)(t + 1); st.w = st.z;
                store_coherent16(hob + blk * 2048 + (tid >> 2) * 16, st);
            }
            // ---- prefetch t+1 (hides first-probe latency under other blocks' tails) ----
            pv = *(const uint2*)((const char*)P + ((long)((t + 1) * 64 + blk)) * 4096 + tid * 8);
            #pragma unroll
            for (int j = 0; j < 16; ++j)
                u[j] = load_cg_sv(voff, (const char*)hob + j * 8192);
            out[(long)eb * RES_STRIDE + (long)t * 1024 + hcol] = hnew;  // overlaps spin
        } else {
            out[(long)eb * RES_STRIDE + (long)t * 1024 + hcol] = hnew;
            out[HT_OFF + eb * 1024 + hcol] = hnew;
            out[CT_OFF + eb * 1024 + hcol] = cReg;
        }
    }
}

extern "C" void kernel_launch(void* const* d_in, const int* in_sizes, int n_in,
                              void* d_out, int out_size, void* d_ws, size_t ws_size,
                              hipStream_t stream) {
    const int*   tgt  = (const int*)d_in[0];
    const float* h0   = (const float*)d_in[1];
    const float* c0   = (const float*)d_in[2];
    const float* embT = (const float*)d_in[5];
    const float* wih  = (const float*)d_in[6];
    const float* whh  = (const float*)d_in[7];
    const float* bih  = (const float*)d_in[8];
    const float* bhh  = (const float*)d_in[9];
    float* out = (float*)d_out;

    char* ws = (char*)d_ws;
    bf16*  Pb   = (bf16*)(ws);                 // 133,955,584 B (block-major P'')
    bf16*  embB = (bf16*)(ws + 133955584);     // 65,536,000 B
    bf16*  wihB = (bf16*)(ws + 199491584);     //  8,388,608 B
    bf16*  whhB = (bf16*)(ws + 207880192);     //  8,388,608 B
    u32x4* hxA  = (u32x4*)(ws + 216268800);    // 131,072 B tagged h exchange (parity 0)
    u32x4* hxB  = (u32x4*)(ws + 216399872);    // 131,072 B tagged h exchange (parity 1)

    // hxB first read at t=1 expecting tag 1 -> prefill with tag 0xFFFFFFFF (never matches)
    (void)hipMemsetAsync(hxB, 0xFF, 131072, stream);

    cvt_kernel<<<32000, 256, 0, stream>>>(embT, embB, 32768000 / 4);
    cvt_kernel<<<4096, 256, 0, stream>>>(wih, wihB, 4194304 / 4);
    cvt_kernel<<<4096, 256, 0, stream>>>(whh, whhB, 4194304 / 4);
    init_state<<<32, 256, 0, stream>>>(h0, hxA);

    dim3 g(32, 128);
    gemm_xproj<<<g, 256, 0, stream>>>(tgt, embB, wihB, bih, bhh, Pb);

    lstm_persist<<<64, 512, 0, stream>>>(Pb, whhB, c0, out, hxA, hxB);
}

// Round 4
// 2777.613 us; speedup vs baseline: 1.0007x; 1.0007x over previous
//
#include <hip/hip_runtime.h>

// Decoder LSTM: B=32, T=511 steps, H=1024, 4H=4096, V=32000
// out = res[32][511][1024] ++ hT[32][1024] ++ cT[32][1024]  (fp32)

typedef __bf16 bf16;
typedef __bf16 bf16x4 __attribute__((ext_vector_type(4)));
typedef __bf16 bf16x8 __attribute__((ext_vector_type(8)));
typedef float f32x4 __attribute__((ext_vector_type(4)));
typedef float f32x16 __attribute__((ext_vector_type(16)));
typedef unsigned int u32x2 __attribute__((ext_vector_type(2)));
typedef unsigned int u32x4 __attribute__((ext_vector_type(4)));

#define M_TOT 16352        // 511*32 rows of x_proj
#define RES_STRIDE 523264  // 511*1024
#define HT_OFF 16744448    // 32*511*1024
#define CT_OFF 16777216    // HT_OFF + 32768

// Coherent (cross-XCD) ops: sc0 sc1 bypass the per-XCD L2, hit L3.
// saddr-form load: uniform SGPR base + per-lane 32-bit voffset.
// NOTE: inline-asm "v" operands must be ext_vector_type, not HIP's uint4 struct.
__device__ __forceinline__ u32x4 load_cg_sv(unsigned voff, const void* sbase) {
    u32x4 r;
    asm volatile("global_load_dwordx4 %0, %1, %2 sc0 sc1"
                 : "=v"(r) : "v"(voff), "s"(sbase));
    return r;
}
__device__ __forceinline__ void store_coherent16(void* p, u32x4 v) {
    asm volatile("global_store_dwordx4 %0, %1, off sc0 sc1" :: "v"(p), "v"(v) : "memory");
}
__device__ __forceinline__ void wait_vm0() {
    asm volatile("s_waitcnt vmcnt(0)" ::: "memory");
}
__device__ __forceinline__ unsigned pack2bf(float a, float b) {
    unsigned ua = (unsigned)__builtin_bit_cast(unsigned short, (bf16)a);
    unsigned ub = (unsigned)__builtin_bit_cast(unsigned short, (bf16)b);
    return ua | (ub << 16);
}
// fast activations: v_exp_f32 + v_rcp_f32 (on the 511-step serial chain)
__device__ __forceinline__ float fsig(float x) {
    return __builtin_amdgcn_rcpf(1.f + __expf(-x));
}
__device__ __forceinline__ float ftanh(float x) {
    float e = __expf(2.f * x);
    return 1.f - 2.f * __builtin_amdgcn_rcpf(e + 1.f);
}

// ---------- fp32 -> bf16 conversion ----------
__global__ void cvt_kernel(const float* __restrict__ src, bf16* __restrict__ dst, int n4) {
    int i = blockIdx.x * blockDim.x + threadIdx.x;
    if (i < n4) {
        float4 v = ((const float4*)src)[i];
        bf16x4 o;
        o[0] = (bf16)v.x; o[1] = (bf16)v.y; o[2] = (bf16)v.z; o[3] = (bf16)v.w;
        ((bf16x4*)dst)[i] = o;
    }
}

// ---------- init h0 as tagged 16B units: unit n = blk*128 + b*4 + (ec>>2) ----------
// unit = { pack(h0,h1), pack(h2,h3), tag, tag }, tag for initial state = 0
__global__ void init_state(const float* __restrict__ h0, u32x4* __restrict__ hxA) {
    int n = blockIdx.x * blockDim.x + threadIdx.x;
    if (n < 8192) {
        int blk = n >> 7, b = (n >> 2) & 31, e4 = n & 3;
        const float* src = h0 + b * 1024 + blk * 16 + e4 * 4;
        u32x4 v;
        v.x = pack2bf(src[0], src[1]);
        v.y = pack2bf(src[2], src[3]);
        v.z = 0u; v.w = 0u;
        hxA[n] = v;
    }
}

// ---------- x_proj GEMM -> P'' block-major: P[(t*64+blk)*2048 + gate*512 + b*16 + c] ----------
__global__ __launch_bounds__(256) void gemm_xproj(
    const int* __restrict__ tgt, const bf16* __restrict__ emb,
    const bf16* __restrict__ wih, const float* __restrict__ bih,
    const float* __restrict__ bhh, bf16* __restrict__ P)
{
    __shared__ bf16 As[128 * 72];
    __shared__ bf16 Bs[128 * 72];
    __shared__ int tok[128];

    const int tid  = threadIdx.x;
    const int lane = tid & 63;
    const int wave = tid >> 6;
    const int wm = wave & 1, wn = wave >> 1;
    const int tileM = blockIdx.y * 128;
    const int tileN = blockIdx.x * 128;

    if (tid < 128) {
        int m = tileM + tid;
        int token = 0;
        if (m < M_TOT) {
            int t = m >> 5, b = m & 31;
            token = tgt[b * 512 + t];
            if ((unsigned)token >= 32000u) token = 0;
        }
        tok[tid] = token;
    }
    __syncthreads();

    f32x4 acc[4][4] = {};

    for (int k0 = 0; k0 < 1024; k0 += 64) {
        #pragma unroll
        for (int i = 0; i < 4; ++i) {
            int chunk = i * 256 + tid;
            int row = chunk >> 3;
            int kc  = (chunk & 7) * 8;
            const bf16* srcA = emb + (long)tok[row] * 1024 + k0 + kc;
            *(uint4*)&As[row * 72 + kc] = *(const uint4*)srcA;
            const bf16* srcB = wih + (long)(tileN + row) * 1024 + k0 + kc;
            *(uint4*)&Bs[row * 72 + kc] = *(const uint4*)srcB;
        }
        __syncthreads();
        #pragma unroll
        for (int kk = 0; kk < 64; kk += 32) {
            bf16x8 a[4], b[4];
            #pragma unroll
            for (int f = 0; f < 4; ++f) {
                a[f] = *(const bf16x8*)&As[(wm * 64 + f * 16 + (lane & 15)) * 72 + kk + (lane >> 4) * 8];
                b[f] = *(const bf16x8*)&Bs[(wn * 64 + f * 16 + (lane & 15)) * 72 + kk + (lane >> 4) * 8];
            }
            #pragma unroll
            for (int mf = 0; mf < 4; ++mf)
                #pragma unroll
                for (int nf = 0; nf < 4; ++nf)
                    acc[mf][nf] = __builtin_amdgcn_mfma_f32_16x16x32_bf16(a[mf], b[nf], acc[mf][nf], 0, 0, 0);
        }
        __syncthreads();
    }

    float bias[4];
    #pragma unroll
    for (int nf = 0; nf < 4; ++nf) {
        int j = tileN + wn * 64 + nf * 16 + (lane & 15);
        bias[nf] = bih[j] + bhh[j];
    }
    #pragma unroll
    for (int mf = 0; mf < 4; ++mf) {
        int mBase = tileM + wm * 64 + mf * 16 + ((lane >> 4) * 4);
        #pragma unroll
        for (int r = 0; r < 4; ++r) {
            int m = mBase + r;
            if (m < M_TOT) {
                int t = m >> 5, bb = m & 31;
                #pragma unroll
                for (int nf = 0; nf < 4; ++nf) {
                    int j = tileN + wn * 64 + nf * 16 + (lane & 15);
                    int gate = j >> 10, jc = j & 1023;
                    int pblk = jc >> 4, pc = jc & 15;
                    P[((long)(t * 64 + pblk)) * 2048 + gate * 512 + bb * 16 + pc]
                        = (bf16)(acc[mf][nf][r] + bias[nf]);
                }
            }
        }
    }
}

// ---------- persistent LSTM: 64 blocks x 512 thr, Lamport-tagged h exchange ----------
// Exchange unit (16B, one-lane dwordx4 store => tear-free): {h0|h1, h2|h3, tag, tag}.
// Consumer at step t reads buf[t&1] expecting tag==t; producer at step t writes
// buf[(t+1)&1] with tag t+1. Safety: no block can store tag t+2 (overwriting the
// buffer a spinner at step t reads) until every block has stored tag t+1, which
// requires every block to have passed spin(t) => max drift 1 step, ping-pong safe.
// R4: spin reissues ONLY stale units (exec-masked), and probes are issued as late
// as possible in the step tail -> poll rounds are request-light.
__global__ __launch_bounds__(512, 1) void lstm_persist(
    const bf16* __restrict__ P, const bf16* __restrict__ whh,
    const float* __restrict__ c0, float* __restrict__ out,
    u32x4* __restrict__ hxA, u32x4* __restrict__ hxB)
{
    __shared__ bf16  hs[32 * 1024];          // h staged, XOR-swizzled (64 KB)
    __shared__ float gs[4 * 64 * 33];        // K-split partials [ks][o][b] (33.8 KB)
    __shared__ bf16  ps[2][2048];            // P'' block, double-buffered (8 KB)

    const int tid  = threadIdx.x;
    const int lane = tid & 63;
    const int wave = tid >> 6;               // 0..7
    const int blk  = blockIdx.x;

    const int tp    = wave & 1;              // col-tile: gates {0,1} or {2,3}
    const int ks    = wave >> 1;             // K quarter 0..3
    const int cc    = lane & 31;
    const int khalf = lane >> 5;
    const int o     = tp * 32 + cc;

    // ---- preload this lane's W_hh B-fragments (16 x bf16x8 = 64 VGPRs) ----
    bf16x8 wreg[16];
    {
        const int gate = tp * 2 + (cc >> 4);
        const int wRow = gate * 1024 + blk * 16 + (cc & 15);
        const bf16* wbase = whh + (long)wRow * 1024 + ks * 256 + khalf * 8;
        #pragma unroll
        for (int i = 0; i < 16; ++i) wreg[i] = *(const bf16x8*)(wbase + i * 16);
    }

    // ---- per-thread epilogue element: (eb, ec) ----
    const int eb = tid >> 4;                 // batch row 0..31
    const int ec = tid & 15;
    const int hcol = blk * 16 + ec;
    float cReg = c0[eb * 1024 + hcol];

    const int m = lane & 31;                 // A-frag row (batch)

    // ---- consumer staging constants (unit n = j*512+tid, all tid-static) ----
    const unsigned voff = (unsigned)(tid << 4);          // byte off within 8KB stripe
    const int srow = (tid >> 2) & 31;                    // the one h-row this thread stages
    const int chb  = ((tid >> 7) << 1) | ((tid & 3) >> 1);
    const int s7   = srow & 7;
    char* hsb = (char*)hs + srow * 2048 + (tid & 1) * 8;

    // ---- prologue prefetch for t=0 ----
    uint2 pv = *(const uint2*)((const char*)P + ((long)blk) * 4096 + tid * 8);
    u32x4 u[16];
    #pragma unroll
    for (int j = 0; j < 16; ++j)
        u[j] = load_cg_sv(voff, (const char*)hxA + j * 8192);

    for (int t = 0; t < 511; ++t) {
        const char* hb = (const char*)((t & 1) ? hxB : hxA);
        const unsigned exptag = (unsigned)t;

        // ---- spin: loads already in flight; poll tags, reissue ONLY stale units ----
        for (;;) {
            wait_vm0();
            __builtin_amdgcn_sched_barrier(0);   // rule #18: pin check after waitcnt
            unsigned bad = 0;
            #pragma unroll
            for (int j = 0; j < 16; ++j) bad |= (u[j].z ^ exptag);
            if (bad == 0) break;
            #pragma unroll
            for (int j = 0; j < 16; ++j)
                if (u[j].z != exptag)                       // exec-masked: fresh lanes idle
                    u[j] = load_cg_sv(voff, hb + j * 8192);
        }

        // ---- stage h (pre-packed pairs) + P'' -> LDS ----
        #pragma unroll
        for (int j = 0; j < 16; ++j)
            *(uint2*)(hsb + (((j * 8 + chb) ^ s7) << 4)) = make_uint2(u[j].x, u[j].y);
        *(uint2*)&ps[t & 1][tid * 4] = pv;
        __syncthreads();

        // ---- K-loop: 16 x mfma_32x32x16, A from LDS, B from regs ----
        f32x16 acc = {};
        #pragma unroll
        for (int i = 0; i < 16; ++i) {
            int ch = ks * 32 + i * 2 + khalf;
            bf16x8 a = *(const bf16x8*)&hs[m * 1024 + ((ch ^ (m & 7)) << 3)];
            acc = __builtin_amdgcn_mfma_f32_32x32x16_bf16(a, wreg[i], acc, 0, 0, 0);
        }

        // ---- write partials to exchange ----
        #pragma unroll
        for (int r = 0; r < 16; ++r) {
            int b = (r & 3) + 8 * (r >> 2) + 4 * khalf;   // C/D row
            gs[(ks * 64 + o) * 33 + b] = acc[r];
        }
        __syncthreads();

        // ---- epilogue: one (eb, hcol) element per thread ----
        float g4[4];
        #pragma unroll
        for (int g = 0; g < 4; ++g) {
            int oo = (g >> 1) * 32 + (g & 1) * 16 + ec;
            float s = gs[(0 * 64 + oo) * 33 + eb] + gs[(1 * 64 + oo) * 33 + eb]
                    + gs[(2 * 64 + oo) * 33 + eb] + gs[(3 * 64 + oo) * 33 + eb];
            g4[g] = s + (float)ps[t & 1][g * 512 + eb * 16 + ec];
        }
        float ig = fsig(g4[0]);
        float fg = fsig(g4[1]);
        float gg = ftanh(g4[2]);
        float og = fsig(g4[3]);
        cReg = fg * cReg + ig * gg;
        float hnew = og * ftanh(cReg);

        if (t < 510) {
            // P'' prefetch for t+1 first (independent, longest latency tolerance)
            pv = *(const uint2*)((const char*)P + ((long)((t + 1) * 64 + blk)) * 4096 + tid * 8);
            // ---- publish h for t+1: quad-pack via DPP, one 16B store per 4 lanes ----
            unsigned w = (unsigned)__builtin_bit_cast(unsigned short, (bf16)hnew);
            unsigned p1  = (unsigned)__builtin_amdgcn_mov_dpp((int)w,   0xB1, 0xF, 0xF, true); // xor1
            unsigned w01 = (tid & 1) ? (p1 | (w << 16)) : (w | (p1 << 16));
            unsigned w23 = (unsigned)__builtin_amdgcn_mov_dpp((int)w01, 0x4E, 0xF, 0xF, true); // xor2
            char* hob = (char*)((t & 1) ? hxA : hxB);
            if ((tid & 3) == 0) {
                u32x4 st;
                st.x = w01; st.y = w23; st.z = (unsigned)(t + 1); st.w = st.z;
                store_coherent16(hob + blk * 2048 + (tid >> 2) * 16, st);
            }
            // result store (plain, L2-absorbed) before probes
            out[(long)eb * RES_STRIDE + (long)t * 1024 + hcol] = hnew;
            // ---- probe prefetch LAST: lands later -> fewer stale units on probe 1 ----
            #pragma unroll
            for (int j = 0; j < 16; ++j)
                u[j] = load_cg_sv(voff, (const char*)hob + j * 8192);
        } else {
            out[(long)eb * RES_STRIDE + (long)t * 1024 + hcol] = hnew;
            out[HT_OFF + eb * 1024 + hcol] = hnew;
            out[CT_OFF + eb * 1024 + hcol] = cReg;
        }
    }
}

extern "C" void kernel_launch(void* const* d_in, const int* in_sizes, int n_in,
                              void* d_out, int out_size, void* d_ws, size_t ws_size,
                              hipStream_t stream) {
    const int*   tgt  = (const int*)d_in[0];
    const float* h0   = (const float*)d_in[1];
    const float* c0   = (const float*)d_in[2];
    const float* embT = (const float*)d_in[5];
    const float* wih  = (const float*)d_in[6];
    const float* whh  = (const float*)d_in[7];
    const float* bih  = (const float*)d_in[8];
    const float* bhh  = (const float*)d_in[9];
    float* out = (float*)d_out;

    char* ws = (char*)d_ws;
    bf16*  Pb   = (bf16*)(ws);                 // 133,955,584 B (block-major P'')
    bf16*  embB = (bf16*)(ws + 133955584);     // 65,536,000 B
    bf16*  wihB = (bf16*)(ws + 199491584);     //  8,388,608 B
    bf16*  whhB = (bf16*)(ws + 207880192);     //  8,388,608 B
    u32x4* hxA  = (u32x4*)(ws + 216268800);    // 131,072 B tagged h exchange (parity 0)
    u32x4* hxB  = (u32x4*)(ws + 216399872);    // 131,072 B tagged h exchange (parity 1)

    // hxB first read at t=1 expecting tag 1 -> prefill with tag 0xFFFFFFFF (never matches)
    (void)hipMemsetAsync(hxB, 0xFF, 131072, stream);

    cvt_kernel<<<32000, 256, 0, stream>>>(embT, embB, 32768000 / 4);
    cvt_kernel<<<4096, 256, 0, stream>>>(wih, wihB, 4194304 / 4);
    cvt_kernel<<<4096, 256, 0, stream>>>(whh, whhB, 4194304 / 4);
    init_state<<<32, 256, 0, stream>>>(h0, hxA);

    dim3 g(32, 128);
    gemm_xproj<<<g, 256, 0, stream>>>(tgt, embB, wihB, bih, bhh, Pb);

    lstm_persist<<<64, 512, 0, stream>>>(Pb, whhB, c0, out, hxA, hxB);
}

// Round 6
// 2251.820 us; speedup vs baseline: 1.2344x; 1.2335x over previous
//
#include <hip/hip_runtime.h>

// Decoder LSTM: B=32, T=511 steps, H=1024, 4H=4096, V=32000
// out = res[32][511][1024] ++ hT[32][1024] ++ cT[32][1024]  (fp32)

typedef __bf16 bf16;
typedef __bf16 bf16x4 __attribute__((ext_vector_type(4)));
typedef __bf16 bf16x8 __attribute__((ext_vector_type(8)));
typedef float f32x4 __attribute__((ext_vector_type(4)));
typedef float f32x16 __attribute__((ext_vector_type(16)));
typedef unsigned int u32x4 __attribute__((ext_vector_type(4)));

#define M_TOT 16352        // 511*32 rows of x_proj
#define RES_STRIDE 523264  // 511*1024
#define HT_OFF 16744448    // 32*511*1024
#define CT_OFF 16777216    // HT_OFF + 32768

// Coherent (cross-XCD) ops: sc0 sc1 bypass the per-XCD L2, hit L3.
__device__ __forceinline__ u32x4 load_coherent16(const void* p) {
    u32x4 r;
    asm volatile("global_load_dwordx4 %0, %1, off sc0 sc1" : "=v"(r) : "v"(p));
    return r;
}
__device__ __forceinline__ unsigned load_cg4(const void* p) {   // no embedded wait
    unsigned r;
    asm volatile("global_load_dword %0, %1, off sc0 sc1" : "=v"(r) : "v"(p));
    return r;
}
__device__ __forceinline__ void store_coherent2(void* p, unsigned int v) {
    asm volatile("global_store_short %0, %1, off sc0 sc1" :: "v"(p), "v"(v) : "memory");
}
__device__ __forceinline__ void store_coherent4(void* p, unsigned int v) {
    asm volatile("global_store_dword %0, %1, off sc0 sc1" :: "v"(p), "v"(v) : "memory");
}
__device__ __forceinline__ void wait_vm0() {
    asm volatile("s_waitcnt vmcnt(0)" ::: "memory");
}
// fast activations: v_exp_f32 + v_rcp_f32 (on the 511-step serial chain)
__device__ __forceinline__ float fsig(float x) {
    return __builtin_amdgcn_rcpf(1.f + __expf(-x));
}
__device__ __forceinline__ float ftanh(float x) {
    float e = __expf(2.f * x);
    return 1.f - 2.f * __builtin_amdgcn_rcpf(e + 1.f);
}

// ---------- fp32 -> bf16 conversion ----------
__global__ void cvt_kernel(const float* __restrict__ src, bf16* __restrict__ dst, int n4) {
    int i = blockIdx.x * blockDim.x + threadIdx.x;
    if (i < n4) {
        float4 v = ((const float4*)src)[i];
        bf16x4 o;
        o[0] = (bf16)v.x; o[1] = (bf16)v.y; o[2] = (bf16)v.z; o[3] = (bf16)v.w;
        ((bf16x4*)dst)[i] = o;
    }
}

// ---------- init h0 in block-major exchange layout: hx[blk*512 + b*16 + c] ----------
__global__ void init_state(const float* __restrict__ h0, bf16* __restrict__ hx) {
    int i = blockIdx.x * blockDim.x + threadIdx.x;
    if (i < 32768) {
        int b = i >> 10, col = i & 1023;
        int blk = col >> 4, c = col & 15;
        hx[blk * 512 + b * 16 + c] = (bf16)h0[i];
    }
}

// ---------- x_proj GEMM -> P'' block-major: P[(t*64+blk)*2048 + gate*512 + b*16 + c] ----------
__global__ __launch_bounds__(256) void gemm_xproj(
    const int* __restrict__ tgt, const bf16* __restrict__ emb,
    const bf16* __restrict__ wih, const float* __restrict__ bih,
    const float* __restrict__ bhh, bf16* __restrict__ P)
{
    __shared__ bf16 As[128 * 72];
    __shared__ bf16 Bs[128 * 72];
    __shared__ int tok[128];

    const int tid  = threadIdx.x;
    const int lane = tid & 63;
    const int wave = tid >> 6;
    const int wm = wave & 1, wn = wave >> 1;
    const int tileM = blockIdx.y * 128;
    const int tileN = blockIdx.x * 128;

    if (tid < 128) {
        int m = tileM + tid;
        int token = 0;
        if (m < M_TOT) {
            int t = m >> 5, b = m & 31;
            token = tgt[b * 512 + t];
            if ((unsigned)token >= 32000u) token = 0;
        }
        tok[tid] = token;
    }
    __syncthreads();

    f32x4 acc[4][4] = {};

    for (int k0 = 0; k0 < 1024; k0 += 64) {
        #pragma unroll
        for (int i = 0; i < 4; ++i) {
            int chunk = i * 256 + tid;
            int row = chunk >> 3;
            int kc  = (chunk & 7) * 8;
            const bf16* srcA = emb + (long)tok[row] * 1024 + k0 + kc;
            *(uint4*)&As[row * 72 + kc] = *(const uint4*)srcA;
            const bf16* srcB = wih + (long)(tileN + row) * 1024 + k0 + kc;
            *(uint4*)&Bs[row * 72 + kc] = *(const uint4*)srcB;
        }
        __syncthreads();
        #pragma unroll
        for (int kk = 0; kk < 64; kk += 32) {
            bf16x8 a[4], b[4];
            #pragma unroll
            for (int f = 0; f < 4; ++f) {
                a[f] = *(const bf16x8*)&As[(wm * 64 + f * 16 + (lane & 15)) * 72 + kk + (lane >> 4) * 8];
                b[f] = *(const bf16x8*)&Bs[(wn * 64 + f * 16 + (lane & 15)) * 72 + kk + (lane >> 4) * 8];
            }
            #pragma unroll
            for (int mf = 0; mf < 4; ++mf)
                #pragma unroll
                for (int nf = 0; nf < 4; ++nf)
                    acc[mf][nf] = __builtin_amdgcn_mfma_f32_16x16x32_bf16(a[mf], b[nf], acc[mf][nf], 0, 0, 0);
        }
        __syncthreads();
    }

    float bias[4];
    #pragma unroll
    for (int nf = 0; nf < 4; ++nf) {
        int j = tileN + wn * 64 + nf * 16 + (lane & 15);
        bias[nf] = bih[j] + bhh[j];
    }
    #pragma unroll
    for (int mf = 0; mf < 4; ++mf) {
        int mBase = tileM + wm * 64 + mf * 16 + ((lane >> 4) * 4);
        #pragma unroll
        for (int r = 0; r < 4; ++r) {
            int m = mBase + r;
            if (m < M_TOT) {
                int t = m >> 5, bb = m & 31;
                #pragma unroll
                for (int nf = 0; nf < 4; ++nf) {
                    int j = tileN + wn * 64 + nf * 16 + (lane & 15);
                    int gate = j >> 10, jc = j & 1023;
                    int pblk = jc >> 4, pc = jc & 15;
                    P[((long)(t * 64 + pblk)) * 2048 + gate * 512 + bb * 16 + pc]
                        = (bf16)(acc[mf][nf][r] + bias[nf]);
                }
            }
        }
    }
}

// ---------- persistent LSTM: 64 blocks x 512 thr, flag protocol + gated chunk loads ----------
// Thread tid's chunk j reads source block sb = j*8 + wave  => wave w depends on exactly
// flags {j*8+w}. Poll per wave (lanes 0..7, dense 4B flags = 2 cachelines) and issue each
// chunk's 16B load the moment its flag is seen: flag trip and data trip overlap.
// Own-block chunk (sb==blk) is pre-ready: own stores were vmcnt(0)+barrier drained before
// the flag store, so post-barrier loads see them without waiting for our own flag.
// Ping-pong safety (= baseline): a block enters step t only after all flags >= t, i.e.
// all blocks finished step t-1; writes at step t go to buf[(t+1)&1], which readers of
// step t-1 (buf[(t-1)&1] = same parity) have fully consumed before setting flag t.
__global__ __launch_bounds__(512, 1) void lstm_persist(
    const bf16* __restrict__ P, const bf16* __restrict__ whh,
    const float* __restrict__ c0, float* __restrict__ out,
    bf16* __restrict__ hxA, bf16* __restrict__ hxB,
    unsigned int* __restrict__ flags)
{
    __shared__ bf16  hs[32 * 1024];          // h staged, XOR-swizzled (64 KB)
    __shared__ float gs[4 * 64 * 33];        // K-split partials [ks][o][b] (33.8 KB)
    __shared__ bf16  ps[2048];               // P'' block for this step (4 KB)

    const int tid  = threadIdx.x;
    const int lane = tid & 63;
    const int wave = tid >> 6;               // 0..7
    const int blk  = blockIdx.x;

    const int tp    = wave & 1;              // col-tile: gates {0,1} or {2,3}
    const int ks    = wave >> 1;             // K quarter 0..3
    const int cc    = lane & 31;
    const int khalf = lane >> 5;
    const int o     = tp * 32 + cc;

    // ---- preload this lane's W_hh B-fragments (16 x bf16x8 = 64 VGPRs) ----
    bf16x8 wreg[16];
    {
        const int gate = tp * 2 + (cc >> 4);
        const int wRow = gate * 1024 + blk * 16 + (cc & 15);
        const bf16* wbase = whh + (long)wRow * 1024 + ks * 256 + khalf * 8;
        #pragma unroll
        for (int i = 0; i < 16; ++i) wreg[i] = *(const bf16x8*)(wbase + i * 16);
    }

    // ---- per-thread epilogue element: (eb, ec) ----
    const int eb = tid >> 4;                 // batch row 0..31
    const int ec = tid & 15;
    const int hcol = blk * 16 + ec;
    float cReg = c0[eb * 1024 + hcol];

    const int m = lane & 31;                 // A-frag row (batch)

    // own chunk: j*8 + wave == blk  =>  wave == blk&7, j == blk>>3
    const unsigned ownbit = (wave == (blk & 7)) ? (1u << (blk >> 3)) : 0u;

    // ---- prologue: P'' for t=0 ----
    uint2 pv = *(const uint2*)((const char*)P + ((long)blk) * 4096 + tid * 8);

    for (int t = 0; t < 511; ++t) {
        const char* hin = (const char*)((t & 1) ? hxB : hxA);
        const unsigned tgtf = (unsigned)t;

        // ---- gated load: poll own-wave flags, issue chunks as they become ready ----
        u32x4 v[8];
        unsigned pend = 0xFFu;
        unsigned newly = ownbit;             // own chunk pre-ready (drained pre-barrier)
        for (;;) {
            #pragma unroll
            for (int j = 0; j < 8; ++j)
                if ((newly >> j) & 1)        // wave-uniform branch, static j
                    v[j] = load_coherent16(hin + (j * 512 + tid) * 16);
            pend &= ~newly;
            if (pend == 0) break;
            unsigned f = 0;
            if (lane < 8) f = load_cg4(flags + (lane * 8 + wave));
            wait_vm0();
            __builtin_amdgcn_sched_barrier(0);   // pin the ballot after the waitcnt
            newly = ((unsigned)__ballot((int)(f >= tgtf)) & 0xFFu) & pend;
        }
        wait_vm0();                          // last-issued chunk loads
        __builtin_amdgcn_sched_barrier(0);

        // ---- stage h (XOR-swizzled) + P'' -> LDS ----
        #pragma unroll
        for (int j = 0; j < 8; ++j) {
            int q = j * 512 + tid;           // 16B chunk id 0..4095
            int sb  = q >> 6;                // source block 0..63
            int idx = q & 63;
            int b   = idx >> 1;              // row 0..31
            int hf  = idx & 1;
            int ch  = sb * 2 + hf;           // 16B chunk within row
            *(u32x4*)&hs[b * 1024 + ((ch ^ (b & 7)) << 3)] = v[j];
        }
        *(uint2*)&ps[tid * 4] = pv;
        __syncthreads();

        // ---- K-loop: 16 x mfma_32x32x16, A from LDS, B from regs ----
        f32x16 acc = {};
        #pragma unroll
        for (int i = 0; i < 16; ++i) {
            int ch = ks * 32 + i * 2 + khalf;
            bf16x8 a = *(const bf16x8*)&hs[m * 1024 + ((ch ^ (m & 7)) << 3)];
            acc = __builtin_amdgcn_mfma_f32_32x32x16_bf16(a, wreg[i], acc, 0, 0, 0);
        }

        // ---- write partials to exchange (gs != hs, no barrier needed before) ----
        #pragma unroll
        for (int r = 0; r < 16; ++r) {
            int b = (r & 3) + 8 * (r >> 2) + 4 * khalf;   // C/D row
            gs[(ks * 64 + o) * 33 + b] = acc[r];
        }
        __syncthreads();

        // ---- epilogue: one (eb, hcol) element per thread ----
        float g4[4];
        #pragma unroll
        for (int g = 0; g < 4; ++g) {
            int oo = (g >> 1) * 32 + (g & 1) * 16 + ec;
            float s = gs[(0 * 64 + oo) * 33 + eb] + gs[(1 * 64 + oo) * 33 + eb]
                    + gs[(2 * 64 + oo) * 33 + eb] + gs[(3 * 64 + oo) * 33 + eb];
            g4[g] = s + (float)ps[g * 512 + eb * 16 + ec];
        }
        float ig = fsig(g4[0]);
        float fg = fsig(g4[1]);
        float gg = ftanh(g4[2]);
        float og = fsig(g4[3]);
        cReg = fg * cReg + ig * gg;
        float hnew = og * ftanh(cReg);

        if (t < 510) {
            bf16 hb = (bf16)hnew;
            unsigned int bits = (unsigned int)__builtin_bit_cast(unsigned short, hb);
            char* hout = (char*)((t & 1) ? hxA : hxB);
            store_coherent2(hout + (blk * 512 + tid) * 2, bits);
            wait_vm0();            // this thread's h store drained to L3
            __syncthreads();       // all threads' h stores drained
            if (tid == 0) store_coherent4(flags + blk, (unsigned)(t + 1));
            pv = *(const uint2*)((const char*)P + ((long)((t + 1) * 64 + blk)) * 4096 + tid * 8);
            out[(long)eb * RES_STRIDE + (long)t * 1024 + hcol] = hnew;
        } else {
            out[(long)eb * RES_STRIDE + (long)t * 1024 + hcol] = hnew;
            out[HT_OFF + eb * 1024 + hcol] = hnew;
            out[CT_OFF + eb * 1024 + hcol] = cReg;
        }
    }
}

extern "C" void kernel_launch(void* const* d_in, const int* in_sizes, int n_in,
                              void* d_out, int out_size, void* d_ws, size_t ws_size,
                              hipStream_t stream) {
    const int*   tgt  = (const int*)d_in[0];
    const float* h0   = (const float*)d_in[1];
    const float* c0   = (const float*)d_in[2];
    const float* embT = (const float*)d_in[5];
    const float* wih  = (const float*)d_in[6];
    const float* whh  = (const float*)d_in[7];
    const float* bih  = (const float*)d_in[8];
    const float* bhh  = (const float*)d_in[9];
    float* out = (float*)d_out;

    char* ws = (char*)d_ws;
    bf16*  Pb   = (bf16*)(ws);                 // 133,955,584 B (block-major P'')
    bf16*  embB = (bf16*)(ws + 133955584);     // 65,536,000 B
    bf16*  wihB = (bf16*)(ws + 199491584);     //  8,388,608 B
    bf16*  whhB = (bf16*)(ws + 207880192);     //  8,388,608 B
    bf16*  hxA  = (bf16*)(ws + 216268800);     // 65,536 B (block-major h exchange)
    bf16*  hxB  = (bf16*)(ws + 216334336);     // 65,536 B
    unsigned int* flags = (unsigned int*)(ws + 216399872);  // 64 dense dword flags

    (void)hipMemsetAsync(flags, 0, 64 * 4, stream);

    cvt_kernel<<<32000, 256, 0, stream>>>(embT, embB, 32768000 / 4);
    cvt_kernel<<<4096, 256, 0, stream>>>(wih, wihB, 4194304 / 4);
    cvt_kernel<<<4096, 256, 0, stream>>>(whh, whhB, 4194304 / 4);
    init_state<<<128, 256, 0, stream>>>(h0, hxA);

    dim3 g(32, 128);
    gemm_xproj<<<g, 256, 0, stream>>>(tgt, embB, wihB, bih, bhh, Pb);

    lstm_persist<<<64, 512, 0, stream>>>(Pb, whhB, c0, out, hxA, hxB, flags);
}